// Round 7
// baseline (139.393 us; speedup 1.0000x reference)
//
#include <hip/hip_runtime.h>
#include <hip/hip_bf16.h>
#include <stdint.h>

typedef __bf16 bf16x8 __attribute__((ext_vector_type(8)));
typedef float  f32x4  __attribute__((ext_vector_type(4)));
typedef unsigned short u16x8 __attribute__((ext_vector_type(8)));

#define NB 32
#define NC 128
#define NH 56
#define NW 56
#define NK 4
#define NCO 128
#define NCR 32
#define NHW 3136
#define TEMPER 30.0f

// ws byte offsets
#define WS_ATTN   0u         // 512 B
#define WS_BC     4096u      // 16 KB
#define WS_ROWSUM 65536u     // f32 [32][58][128] = 950,272 B
#define WS_WC     1048576u   // bf16 [32][9][128][128] = 9,437,184 B
#define WS_XT     10485760u  // bf16 [32][58][58][128] = 27,557,888 B

__global__ void xt_kernel(const float* __restrict__ x, __hip_bfloat16* __restrict__ xt,
                          float* __restrict__ rowsum) {
  __shared__ float lds[58 * 133];
  int xcd = blockIdx.x & 7;
  int j   = blockIdx.x >> 3;               // 0..231
  int b   = xcd * 4 + j / 58;
  int hp  = j % 58;
  int blk = b * 58 + hp;
  int h = hp - 1;
  bool hin = (h >= 0) && (h < NH);
  int tid = threadIdx.x;
  if (hin) {
    const float* xrow = x + ((size_t)b * NC) * NHW + (size_t)h * NW;
    for (int i = tid; i < 128 * 14; i += 256) {
      int c = i / 14;
      int w4 = (i - c * 14) * 4;
      float4 v = *(const float4*)(xrow + (size_t)c * NHW + w4);
      int base = (w4 + 1) * 133 + c;
      lds[base]         = v.x;
      lds[base + 133]   = v.y;
      lds[base + 2*133] = v.z;
      lds[base + 3*133] = v.w;
    }
  }
  __syncthreads();
  __hip_bfloat16* orow = xt + (size_t)blk * (58 * 128);
  for (int i = tid; i < 58 * 16; i += 256) {
    int wp = i >> 4;
    int cg = (i & 15) << 3;
    u16x8 o;
    if (!hin || wp == 0 || wp == 57) {
      o = (u16x8)0;
    } else {
      const float* src = lds + wp * 133 + cg;
      #pragma unroll
      for (int jx = 0; jx < 8; ++jx) {
        union { __hip_bfloat16 b; unsigned short u; } cv;
        cv.b = __float2bfloat16(src[jx]);
        o[jx] = cv.u;
      }
    }
    *(u16x8*)(orow + wp * 128 + cg) = o;
  }
  if (hin && tid < 128) {
    float s = 0.f;
    #pragma unroll 8
    for (int wp = 1; wp <= 56; ++wp) s += lds[wp * 133 + tid];
    rowsum[(size_t)blk * 128 + tid] = s;
  }
}

__global__ void attn_kernel(const float* __restrict__ rowsum, const float* __restrict__ aw1,
                            const float* __restrict__ aw2, const float* __restrict__ bias,
                            float* __restrict__ attn, float* __restrict__ bc_out) {
  int b = blockIdx.x;
  __shared__ float sp[NC], h1[NCR], at[NK];
  int t = threadIdx.x;
  if (t < NC) {
    float s = 0.f;
    for (int hp = 1; hp <= 56; ++hp) s += rowsum[((size_t)b * 58 + hp) * 128 + t];
    sp[t] = s * (1.0f / (float)NHW);
  }
  __syncthreads();
  if (t < NCR) {
    float s = 0.f;
    for (int c = 0; c < NC; ++c) s += aw1[t*NC + c] * sp[c];
    h1[t] = s > 0.f ? s : 0.f;
  }
  __syncthreads();
  if (t == 0) {
    float lg[NK], mx = -1e30f;
    for (int k = 0; k < NK; ++k) {
      float s = 0.f;
      for (int r = 0; r < NCR; ++r) s += aw2[k*NCR + r] * h1[r];
      lg[k] = s * (1.0f/TEMPER);
      mx = fmaxf(mx, lg[k]);
    }
    float den = 0.f, e[NK];
    for (int k = 0; k < NK; ++k) { e[k] = expf(lg[k]-mx); den += e[k]; }
    float inv = 1.0f/den;
    for (int k = 0; k < NK; ++k) { at[k] = e[k]*inv; attn[b*NK+k] = at[k]; }
  }
  __syncthreads();
  if (t < NCO) {
    float s = 0.f;
    for (int k = 0; k < NK; ++k) s += at[k] * bias[k*NCO + t];
    bc_out[b*NCO + t] = s;
  }
}

__global__ void combine_kernel(const float* __restrict__ W, const float* __restrict__ attn,
                               __hip_bfloat16* __restrict__ wc) {
  int gid = blockIdx.x;                     // 256 blocks
  int bg  = gid >> 6;
  int tcell = (gid & 63) * 256 + threadIdx.x;
  int co = tcell >> 7, ci = tcell & 127;
  float w[4][9];
  const float* wp = W + ((size_t)co * 128 + ci) * 9;
  #pragma unroll
  for (int k = 0; k < 4; ++k)
    #pragma unroll
    for (int j = 0; j < 9; ++j)
      w[k][j] = wp[(size_t)k * 147456 + j];
  for (int b = bg * 8; b < bg * 8 + 8; ++b) {
    float a0 = attn[b*4+0], a1 = attn[b*4+1], a2 = attn[b*4+2], a3 = attn[b*4+3];
    #pragma unroll
    for (int j = 0; j < 9; ++j) {
      float v = a0*w[0][j] + a1*w[1][j] + a2*w[2][j] + a3*w[3][j];
      wc[(((size_t)b*9 + j) * 128 + co) * 128 + ci] = __float2bfloat16(v);
    }
  }
}

// ------------------------------ conv ------------------------------
// V0: production (R2-best config: 4 waves x (64co x 112pos), per-khw A-loads
//     from L2, 6-row double-buffered LDS B, grid 448).
// V3: identical, grid 112 (<256 CUs -> solo block per CU) -> measures pure
//     block serial time, writes same-correct values to d_out.
// V1: A-loads + MFMA + barriers only (no staging / no ds_reads) -> scratch.
// V2: staging + ds_reads + A-loads, NO MFMA (frags kept alive via XOR
//     checksum, rule #17) -> scratch.
#define RS 2368   // shorts per padded LDS row (296 16B-slots, %8==0)
#define CS 40     // shorts per col cell
#define BUFSH (6*RS)

#define GLOAD16(src, dst) \
  __builtin_amdgcn_global_load_lds( \
    (const __attribute__((address_space(1))) unsigned int*)(src), \
    (__attribute__((address_space(3))) unsigned int*)(dst), 16, 0, 0)

template<int V>
__global__ __launch_bounds__(256, 2) void conv_kernel(
    const unsigned short* __restrict__ xt,
    const unsigned short* __restrict__ wc,
    const float* __restrict__ bc,
    float* __restrict__ out) {
  __shared__ __align__(16) unsigned short lds_x[2*BUFSH];
  const int tid  = threadIdx.x;
  const int lane = tid & 63;
  const int wv   = tid >> 6;
  const int wave_m = wv & 1;
  const int wave_n = wv >> 1;
  const int bid = blockIdx.x;
  const int xcd = bid & 7;
  const int jj  = bid >> 3;
  const int b   = xcd * 4 + (jj / 14);
  const int r0  = (jj % 14) * 4;
  const int li = lane & 15;
  const int kg = lane >> 4;

  int srcoff[7];
  #pragma unroll
  for (int i = 0; i < 7; ++i) {
    int q = i*256 + tid;
    int r = q / 296;
    int sl = q - r*296;
    int col = sl / 5;
    int part = sl - col*5;
    if (q < 1776 && col < 58 && part < 4)
      srcoff[i] = ((r0 + r)*58 + col)*128 + part*8;
    else
      srcoff[i] = -1;
  }

  int rB[7], cB[7], xoff[7];
  #pragma unroll
  for (int f = 0; f < 7; ++f) {
    int pos = wave_n*112 + f*16 + li;
    rB[f] = pos / 56;
    cB[f] = pos - rB[f]*56;
    xoff[f] = rB[f]*RS + cB[f]*CS + kg*8;
  }
  const f32x4 vzero = {0.f, 0.f, 0.f, 0.f};
  f32x4 acc[4][7];
  #pragma unroll
  for (int mo = 0; mo < 4; ++mo)
    #pragma unroll
    for (int f = 0; f < 7; ++f) acc[mo][f] = vzero;

  uint32_t c0 = 0, c1 = 0, c2 = 0, c3 = 0;   // V2 keep-alive checksum

  const unsigned short* xtg = xt + (size_t)b*(58*58*128);
  const unsigned short* wcA = wc + (size_t)b*(9*128*128) + (wave_m*64 + li)*128 + kg*8;

  #define STAGE(bufidx, cc) do { \
    unsigned short* dbase = lds_x + (bufidx)*BUFSH; \
    _Pragma("unroll") \
    for (int i = 0; i < 7; ++i) { \
      if (srcoff[i] >= 0) \
        GLOAD16(xtg + srcoff[i] + (cc)*32, dbase + i*2048 + wv*512); \
    } \
  } while (0)

  if (V != 1) STAGE(0, 0);
  __syncthreads();

  for (int cc = 0; cc < 4; ++cc) {
    if (V != 1 && cc < 3) STAGE((cc + 1) & 1, cc + 1);
    const unsigned short* bx = lds_x + (cc & 1)*BUFSH;
    #pragma unroll
    for (int khw = 0; khw < 9; ++khw) {
      const int kh = khw / 3;
      const int kw = khw - kh*3;
      const int koff = kh*RS + kw*CS;
      bf16x8 af[4];
      #pragma unroll
      for (int mo = 0; mo < 4; ++mo)
        af[mo] = *(const bf16x8*)(wcA + khw*16384 + mo*2048 + cc*32);
      if (V == 1) {
        // no LDS path: MFMA on A-frags only (junk values, real dependencies)
        #pragma unroll
        for (int mo = 0; mo < 4; ++mo)
          #pragma unroll
          for (int f = 0; f < 7; ++f)
            acc[mo][f] = __builtin_amdgcn_mfma_f32_16x16x32_bf16(
                af[mo], af[(mo + (f & 3)) & 3], acc[mo][f], 0, 0, 0);
      } else {
        bf16x8 bfr[7];
        #pragma unroll
        for (int f = 0; f < 7; ++f)
          bfr[f] = *(const bf16x8*)(bx + xoff[f] + koff);
        if (V == 2) {
          // consume all frags without MFMA (keep loads live)
          #pragma unroll
          for (int f = 0; f < 7; ++f) {
            const uint32_t* p = (const uint32_t*)&bfr[f];
            c0 ^= p[0]; c1 ^= p[1]; c2 ^= p[2]; c3 ^= p[3];
          }
          #pragma unroll
          for (int mo = 0; mo < 4; ++mo) {
            const uint32_t* p = (const uint32_t*)&af[mo];
            c0 ^= p[0]; c1 ^= p[1]; c2 ^= p[2]; c3 ^= p[3];
          }
        } else {
          #pragma unroll
          for (int mo = 0; mo < 4; ++mo)
            #pragma unroll
            for (int f = 0; f < 7; ++f)
              acc[mo][f] = __builtin_amdgcn_mfma_f32_16x16x32_bf16(af[mo], bfr[f], acc[mo][f], 0, 0, 0);
        }
      }
    }
    __syncthreads();
  }

  if (V == 0 || V == 3) {
    float* ob = out + (size_t)b*NCO*NHW;
    #pragma unroll
    for (int mo = 0; mo < 4; ++mo) {
      #pragma unroll
      for (int rg = 0; rg < 4; ++rg) {
        const int co = wave_m*64 + mo*16 + kg*4 + rg;
        const float bv = bc[b*NCO + co];
        float* orow = ob + (size_t)co*NHW;
        #pragma unroll
        for (int f = 0; f < 7; ++f)
          orow[(r0 + rB[f])*56 + cB[f]] = acc[mo][f][rg] + bv;
      }
    }
  } else if (V == 1) {
    float s = 0.f;
    #pragma unroll
    for (int mo = 0; mo < 4; ++mo)
      #pragma unroll
      for (int f = 0; f < 7; ++f)
        s += acc[mo][f][0] + acc[mo][f][1] + acc[mo][f][2] + acc[mo][f][3];
    out[bid*256 + tid] = s;
  } else {
    union { uint32_t u; float f; } cv;
    cv.u = c0 ^ c1 ^ c2 ^ c3;
    out[bid*256 + tid] = cv.f;
  }
}

extern "C" void kernel_launch(void* const* d_in, const int* in_sizes, int n_in,
                              void* d_out, int out_size, void* d_ws, size_t ws_size,
                              hipStream_t stream) {
  const float* x   = (const float*)d_in[0];
  const float* W   = (const float*)d_in[1];
  const float* bia = (const float*)d_in[2];
  const float* aw1 = (const float*)d_in[3];
  const float* aw2 = (const float*)d_in[4];
  float* out = (float*)d_out;
  char* ws = (char*)d_ws;
  float* attn   = (float*)(ws + WS_ATTN);
  float* bcm    = (float*)(ws + WS_BC);
  float* rowsum = (float*)(ws + WS_ROWSUM);
  __hip_bfloat16* wc = (__hip_bfloat16*)(ws + WS_WC);
  __hip_bfloat16* xt = (__hip_bfloat16*)(ws + WS_XT);
  float* scratch = (float*)(ws + WS_WC);   // reused post-consumption by V1/V2

  xt_kernel<<<NB*58, 256, 0, stream>>>(x, xt, rowsum);
  attn_kernel<<<NB, 128, 0, stream>>>(rowsum, aw1, aw2, bia, attn, bcm);
  combine_kernel<<<256, 256, 0, stream>>>(W, attn, wc);
  conv_kernel<0><<<448, 256, 0, stream>>>((const unsigned short*)xt,
                                          (const unsigned short*)wc, bcm, out);
  // --- diagnostic ablations (solo-block residency, grid 112 < 256 CUs) ---
  conv_kernel<3><<<112, 256, 0, stream>>>((const unsigned short*)xt,
                                          (const unsigned short*)wc, bcm, out);
  conv_kernel<1><<<112, 256, 0, stream>>>((const unsigned short*)xt,
                                          (const unsigned short*)wc, bcm, scratch);
  conv_kernel<2><<<112, 256, 0, stream>>>((const unsigned short*)xt,
                                          (const unsigned short*)wc, bcm, scratch);
}

// Round 8
// 66.405 us; speedup vs baseline: 2.0991x; 2.0991x over previous
//
#include <hip/hip_runtime.h>
#include <hip/hip_bf16.h>
#include <stdint.h>

typedef __bf16 bf16x8 __attribute__((ext_vector_type(8)));
typedef float  f32x4  __attribute__((ext_vector_type(4)));
typedef unsigned short u16x8 __attribute__((ext_vector_type(8)));
typedef unsigned int   u32x4 __attribute__((ext_vector_type(4)));

#define NB 32
#define NC 128
#define NH 56
#define NW 56
#define NK 4
#define NCO 128
#define NCR 32
#define NHW 3136
#define TEMPER 30.0f

// ws byte offsets
#define WS_ATTN   0u         // 512 B
#define WS_BC     4096u      // 16 KB
#define WS_ROWSUM 65536u     // f32 [32][58][128] = 950,272 B
#define WS_WC     1048576u   // bf16 [32][9][128][128] = 9,437,184 B
#define WS_XT     10485760u  // bf16 [32][58][58][128] = 27,557,888 B

// fp32 NCHW -> bf16 [b][hp=58][wp=58][c=128] with zero halo, via LDS transpose.
// XCD-aligned to conv's b-map. Emits rowsum (pool fused).
__global__ void xt_kernel(const float* __restrict__ x, __hip_bfloat16* __restrict__ xt,
                          float* __restrict__ rowsum) {
  __shared__ float lds[58 * 133];
  int xcd = blockIdx.x & 7;
  int j   = blockIdx.x >> 3;               // 0..231
  int b   = xcd * 4 + j / 58;
  int hp  = j % 58;
  int blk = b * 58 + hp;
  int h = hp - 1;
  bool hin = (h >= 0) && (h < NH);
  int tid = threadIdx.x;
  if (hin) {
    const float* xrow = x + ((size_t)b * NC) * NHW + (size_t)h * NW;
    for (int i = tid; i < 128 * 14; i += 256) {
      int c = i / 14;
      int w4 = (i - c * 14) * 4;
      float4 v = *(const float4*)(xrow + (size_t)c * NHW + w4);
      int base = (w4 + 1) * 133 + c;
      lds[base]         = v.x;
      lds[base + 133]   = v.y;
      lds[base + 2*133] = v.z;
      lds[base + 3*133] = v.w;
    }
  }
  __syncthreads();
  __hip_bfloat16* orow = xt + (size_t)blk * (58 * 128);
  for (int i = tid; i < 58 * 16; i += 256) {
    int wp = i >> 4;
    int cg = (i & 15) << 3;
    u16x8 o;
    if (!hin || wp == 0 || wp == 57) {
      o = (u16x8)0;
    } else {
      const float* src = lds + wp * 133 + cg;
      #pragma unroll
      for (int jx = 0; jx < 8; ++jx) {
        union { __hip_bfloat16 b; unsigned short u; } cv;
        cv.b = __float2bfloat16(src[jx]);
        o[jx] = cv.u;
      }
    }
    *(u16x8*)(orow + wp * 128 + cg) = o;
  }
  if (hin && tid < 128) {
    float s = 0.f;
    #pragma unroll 8
    for (int wp = 1; wp <= 56; ++wp) s += lds[wp * 133 + tid];
    rowsum[(size_t)blk * 128 + tid] = s;
  }
}

__global__ void attn_kernel(const float* __restrict__ rowsum, const float* __restrict__ aw1,
                            const float* __restrict__ aw2, const float* __restrict__ bias,
                            float* __restrict__ attn, float* __restrict__ bc_out) {
  int b = blockIdx.x;
  __shared__ float sp[NC], h1[NCR], at[NK];
  int t = threadIdx.x;
  if (t < NC) {
    float s = 0.f;
    for (int hp = 1; hp <= 56; ++hp) s += rowsum[((size_t)b * 58 + hp) * 128 + t];
    sp[t] = s * (1.0f / (float)NHW);
  }
  __syncthreads();
  if (t < NCR) {
    float s = 0.f;
    for (int c = 0; c < NC; ++c) s += aw1[t*NC + c] * sp[c];
    h1[t] = s > 0.f ? s : 0.f;
  }
  __syncthreads();
  if (t == 0) {
    float lg[NK], mx = -1e30f;
    for (int k = 0; k < NK; ++k) {
      float s = 0.f;
      for (int r = 0; r < NCR; ++r) s += aw2[k*NCR + r] * h1[r];
      lg[k] = s * (1.0f/TEMPER);
      mx = fmaxf(mx, lg[k]);
    }
    float den = 0.f, e[NK];
    for (int k = 0; k < NK; ++k) { e[k] = expf(lg[k]-mx); den += e[k]; }
    float inv = 1.0f/den;
    for (int k = 0; k < NK; ++k) { at[k] = e[k]*inv; attn[b*NK+k] = at[k]; }
  }
  __syncthreads();
  if (t < NCO) {
    float s = 0.f;
    for (int k = 0; k < NK; ++k) s += at[k] * bias[k*NCO + t];
    bc_out[b*NCO + t] = s;
  }
}

__global__ void combine_kernel(const float* __restrict__ W, const float* __restrict__ attn,
                               __hip_bfloat16* __restrict__ wc) {
  int gid = blockIdx.x;                     // 256 blocks
  int bg  = gid >> 6;
  int tcell = (gid & 63) * 256 + threadIdx.x;
  int co = tcell >> 7, ci = tcell & 127;
  float w[4][9];
  const float* wp = W + ((size_t)co * 128 + ci) * 9;
  #pragma unroll
  for (int k = 0; k < 4; ++k)
    #pragma unroll
    for (int j = 0; j < 9; ++j)
      w[k][j] = wp[(size_t)k * 147456 + j];
  for (int b = bg * 8; b < bg * 8 + 8; ++b) {
    float a0 = attn[b*4+0], a1 = attn[b*4+1], a2 = attn[b*4+2], a3 = attn[b*4+3];
    #pragma unroll
    for (int j = 0; j < 9; ++j) {
      float v = a0*w[0][j] + a1*w[1][j] + a2*w[2][j] + a3*w[3][j];
      wc[(((size_t)b*9 + j) * 128 + co) * 128 + ci] = __float2bfloat16(v);
    }
  }
}

// ------------------------------ conv ------------------------------
// m97-pattern rebuild: inner loop is PURE ds_read + MFMA (lgkmcnt only);
// exactly one vmcnt drain per cc (K=288 step). No global loads inside the
// MFMA loop (R2-R6 showed per-khw A-loads entangle vmcnt with the B-prefetch
// queue and serialize everything).
// Block = 128co x 448pos (8 out rows), 8 waves (wave 64co x 112pos).
// Grid 224 (8 XCD x 28): single round, 1 block/CU, 2 waves/SIMD.
// A: reg-staged (global->VGPR->ds_write) into [khw][co][40sh] (80B co-stride,
//    slot%8 spread perfect -> conflict-free af reads).
// B: linear global_load_lds into padded rows (RS=2368 shorts, 296 slots %8==0).
#define RS 2368
#define CS 40
#define AKS 5120   // shorts per khw slab of lds_a (128 co * 40)

#define GLOAD16(src, dst) \
  __builtin_amdgcn_global_load_lds( \
    (const __attribute__((address_space(1))) unsigned int*)(src), \
    (__attribute__((address_space(3))) unsigned int*)(dst), 16, 0, 0)

__global__ __launch_bounds__(512, 2) void conv_kernel(
    const unsigned short* __restrict__ xt,
    const unsigned short* __restrict__ wc,
    const float* __restrict__ bc,
    float* __restrict__ out) {
  __shared__ __align__(16) unsigned short lds_a[9*AKS];   // 92,160 B
  __shared__ __align__(16) unsigned short lds_b[10*RS];   // 47,360 B
  const int tid  = threadIdx.x;        // 0..511
  const int lane = tid & 63;
  const int wv   = tid >> 6;           // 0..7
  const int wm   = wv >> 2;            // co strip *64
  const int wn   = wv & 3;             // pos strip *112
  const int bid  = blockIdx.x;         // 224 = 8*28
  const int xcd  = bid & 7;
  const int jj   = bid >> 3;           // 0..27
  const int b    = xcd*4 + jj/7;
  const int r0   = (jj % 7) * 8;       // 8 out rows per block
  const int li   = lane & 15;
  const int kg   = lane >> 4;

  // B staging map: 10 rows x 296 slots = 2960; 6 iters x 512 threads
  int srcB[6];
  #pragma unroll
  for (int i = 0; i < 6; ++i) {
    int q = i*512 + tid;
    int r = q / 296;
    int sl = q - r*296;
    int col = sl / 5;
    int part = sl - col*5;
    srcB[i] = (q < 2960 && col < 58 && part < 4)
              ? ((r0 + r)*58 + col)*128 + part*8 : -1;
  }
  // A staging map: 4608 slots = 9 iters x 512 threads (exact)
  int aS[9], aD[9];
  #pragma unroll
  for (int i = 0; i < 9; ++i) {
    int s = i*512 + tid;
    int khw = s >> 9;
    int co  = (s & 511) >> 2;
    int part = s & 3;
    aS[i] = (khw*128 + co)*128 + part*8;   // + cc*32 at stage time
    aD[i] = (khw*128 + co)*40 + part*8;
  }

  int xoff[7];
  #pragma unroll
  for (int f = 0; f < 7; ++f) {
    int pos = wn*112 + f*16 + li;          // 0..447
    int rB = pos / 56;
    int cB = pos - rB*56;
    xoff[f] = rB*RS + cB*CS + kg*8;
  }
  const int aRead = (wm*64 + li)*40 + kg*8;

  const f32x4 vzero = {0.f, 0.f, 0.f, 0.f};
  f32x4 acc[4][7];
  #pragma unroll
  for (int mo = 0; mo < 4; ++mo)
    #pragma unroll
    for (int f = 0; f < 7; ++f) acc[mo][f] = vzero;

  const unsigned short* xtg = xt + (size_t)b*(58*58*128);
  const unsigned short* wcg = wc + (size_t)b*(9*128*128);

  for (int cc = 0; cc < 4; ++cc) {
    // A global loads to regs (issued before the barrier; latency overlaps
    // other waves' compute tail). 9 x 16B per thread.
    u32x4 areg[9];
    #pragma unroll
    for (int i = 0; i < 9; ++i)
      areg[i] = *(const u32x4*)(wcg + aS[i] + cc*32);

    __syncthreads();   // all waves done reading lds_a/lds_b of previous cc

    // B: direct global->LDS (linear dest, padded-row layout via src map)
    #pragma unroll
    for (int i = 0; i < 6; ++i)
      if (srcB[i] >= 0)
        GLOAD16(xtg + srcB[i] + cc*32, lds_b + (i*512 + wv*64)*8);
    // A: ds_write staged regs (compiler inserts vmcnt wait for areg only;
    // B gloads issued after stay in flight)
    #pragma unroll
    for (int i = 0; i < 9; ++i)
      *(u32x4*)(lds_a + aD[i]) = areg[i];

    __syncthreads();   // one vmcnt(0)+lgkmcnt(0) drain per cc — staged data ready

    #pragma unroll
    for (int khw = 0; khw < 9; ++khw) {
      const int kh = khw / 3;
      const int kw = khw - kh*3;
      bf16x8 af[4];
      #pragma unroll
      for (int mo = 0; mo < 4; ++mo)
        af[mo] = *(const bf16x8*)(lds_a + khw*AKS + aRead + mo*640);
      const int koff = kh*RS + kw*CS;
      bf16x8 bfr[7];
      #pragma unroll
      for (int f = 0; f < 7; ++f)
        bfr[f] = *(const bf16x8*)(lds_b + xoff[f] + koff);
      __builtin_amdgcn_s_setprio(1);
      #pragma unroll
      for (int mo = 0; mo < 4; ++mo)
        #pragma unroll
        for (int f = 0; f < 7; ++f)
          acc[mo][f] = __builtin_amdgcn_mfma_f32_16x16x32_bf16(af[mo], bfr[f], acc[mo][f], 0, 0, 0);
      __builtin_amdgcn_s_setprio(0);
    }
  }

  float* ob = out + (size_t)b*NCO*NHW;
  #pragma unroll
  for (int mo = 0; mo < 4; ++mo) {
    #pragma unroll
    for (int rg = 0; rg < 4; ++rg) {
      const int co = wm*64 + mo*16 + kg*4 + rg;
      const float bv = bc[b*NCO + co];
      float* orow = ob + (size_t)co*NHW;
      #pragma unroll
      for (int f = 0; f < 7; ++f) {
        int pos = wn*112 + f*16 + li;
        int rB = pos / 56;
        int cB = pos - rB*56;
        orow[(r0 + rB)*56 + cB] = acc[mo][f][rg] + bv;
      }
    }
  }
}

extern "C" void kernel_launch(void* const* d_in, const int* in_sizes, int n_in,
                              void* d_out, int out_size, void* d_ws, size_t ws_size,
                              hipStream_t stream) {
  const float* x   = (const float*)d_in[0];
  const float* W   = (const float*)d_in[1];
  const float* bia = (const float*)d_in[2];
  const float* aw1 = (const float*)d_in[3];
  const float* aw2 = (const float*)d_in[4];
  float* out = (float*)d_out;
  char* ws = (char*)d_ws;
  float* attn   = (float*)(ws + WS_ATTN);
  float* bcm    = (float*)(ws + WS_BC);
  float* rowsum = (float*)(ws + WS_ROWSUM);
  __hip_bfloat16* wc = (__hip_bfloat16*)(ws + WS_WC);
  __hip_bfloat16* xt = (__hip_bfloat16*)(ws + WS_XT);

  xt_kernel<<<NB*58, 256, 0, stream>>>(x, xt, rowsum);
  attn_kernel<<<NB, 128, 0, stream>>>(rowsum, aw1, aw2, bia, attn, bcm);
  combine_kernel<<<256, 256, 0, stream>>>(W, attn, wc);
  conv_kernel<<<224, 512, 0, stream>>>((const unsigned short*)xt,
                                       (const unsigned short*)wc, bcm, out);
}